// Round 2
// baseline (218.127 us; speedup 1.0000x reference)
//
#include <hip/hip_runtime.h>
#include <stdint.h>

// DotProductAttention, B=8 S=4096 D=64 fp32, key-masked at valid_len[b].
// Strategy: error-compensated bf16 MFMA flash attention.
//   - Pre-pass splits K,V into bf16 hi/lo and packs them per-32-key-chunk in
//     exactly the 16B-unit order the MFMA fragment reads want (conflict-free
//     ds_read_b128, staging = linear 16KB copy).
//   - Main kernel: 512 blocks x 128 thr (2 waves x 32 q-rows). Swapped-operand
//     QK^T (mfma(K,Q)) so each lane owns one q-row's scores; online softmax
//     with defer-max (THR=8); P split hi/lo through per-wave LDS; PV mfma.
//   - QK = QhKh+QhKl+QlKh, PV = PhVh+PhVl+PlVh: rel err ~2^-17 -> out ~1e-4.
// Masked keys are simply skipped (exp(-1e6 - m) == 0 exactly in fp32).

constexpr int BB = 8;
constexpr int SS = 4096;
constexpr int DH = 64;
constexpr int CH = 32;              // keys per chunk
constexpr int NKT = SS / CH;        // 128 chunks per batch
constexpr int TILE_SHORTS = 8192;   // 16 KB: Khi 4K | Klo 4K | Vhi 4K | Vlo 4K

typedef short  bfrag  __attribute__((ext_vector_type(8)));   // 8 bf16 (4 VGPR)
typedef float  f32x16 __attribute__((ext_vector_type(16)));
typedef short  sv4    __attribute__((ext_vector_type(4)));
typedef unsigned int uv4 __attribute__((ext_vector_type(4)));

__device__ __forceinline__ unsigned short f2bf(float x) {
  unsigned u = __builtin_bit_cast(unsigned, x);
  u += 0x7fffu + ((u >> 16) & 1u);   // RNE (finite inputs)
  return (unsigned short)(u >> 16);
}
__device__ __forceinline__ float bf2f(unsigned short h) {
  return __builtin_bit_cast(float, ((unsigned)h) << 16);
}

// ---------------- pre-pass: split+tile K and V ----------------
// ws tile (b,kt): 16KB = {Khi[d8 0..7][key 0..31][8], Klo same,
//                         Vhi[k8 0..3][d 0..63][8],  Vlo same}
__global__ __launch_bounds__(256) void prepack(
    const float* __restrict__ K, const float* __restrict__ V,
    short* __restrict__ ws) {
  const int b  = blockIdx.x >> 7;
  const int kt = blockIdx.x & 127;
  const int t  = threadIdx.x;
  short* tile = ws + (size_t)(b * NKT + kt) * TILE_SHORTS;

  {  // K unit t: d8 = t>>5, key = t&31 ; reads K[b][kt*32+key][d8*8 .. +8)
    const int d8 = t >> 5, key = t & 31;
    const float* src = K + ((size_t)b * SS + kt * CH + key) * DH + d8 * 8;
    float4 a = ((const float4*)src)[0];
    float4 c = ((const float4*)src)[1];
    float v[8] = {a.x, a.y, a.z, a.w, c.x, c.y, c.z, c.w};
    bfrag hi, lo;
#pragma unroll
    for (int j = 0; j < 8; ++j) {
      unsigned short h = f2bf(v[j]);
      hi[j] = (short)h;
      lo[j] = (short)f2bf(v[j] - bf2f(h));
    }
    *(bfrag*)(tile + t * 8)        = hi;
    *(bfrag*)(tile + 2048 + t * 8) = lo;
  }
  {  // V unit t: k8 = t>>6, d = t&63 ; reads V[b][kt*32+k8*8+j][d]
    const int k8 = t >> 6, d = t & 63;
    const float* src = V + ((size_t)b * SS + kt * CH + k8 * 8) * DH + d;
    bfrag hi, lo;
#pragma unroll
    for (int j = 0; j < 8; ++j) {
      float x = src[j * DH];
      unsigned short h = f2bf(x);
      hi[j] = (short)h;
      lo[j] = (short)f2bf(x - bf2f(h));
    }
    *(bfrag*)(tile + 4096 + t * 8) = hi;
    *(bfrag*)(tile + 6144 + t * 8) = lo;
  }
}

// ---------------- main fused attention ----------------
__global__ __launch_bounds__(128, 2) void attn_mfma(
    const float* __restrict__ Q, const short* __restrict__ wsT,
    const int* __restrict__ VL, float* __restrict__ Out) {
  __shared__ __align__(16) short sKV[TILE_SHORTS];       // 16 KB staged chunk
  __shared__ __align__(16) short sP[2][2][4][32][8];     // [wave][hi/lo][k8][q][8]

  const int tid = threadIdx.x;
  const int w   = tid >> 6;
  const int l   = tid & 63;
  const int hi5 = l >> 5;
  const int l31 = l & 31;
  const int b   = blockIdx.x >> 6;
  const int qt  = blockIdx.x & 63;
  const int vlen = VL[b];

  // ---- Q fragments (B-operand: col = l31 = q-row), pre-scaled by 1/8 ----
  bfrag qh[4], ql[4];
  {
    const float* qsrc = Q + ((size_t)b * SS + qt * 64 + w * 32 + l31) * DH;
#pragma unroll
    for (int dt = 0; dt < 4; ++dt) {
      const float* p = qsrc + dt * 16 + hi5 * 8;
      float4 a = ((const float4*)p)[0];
      float4 c = ((const float4*)p)[1];
      float v[8] = {a.x, a.y, a.z, a.w, c.x, c.y, c.z, c.w};
#pragma unroll
      for (int j = 0; j < 8; ++j) {
        float x = v[j] * 0.125f;
        unsigned short h = f2bf(x);
        qh[dt][j] = (short)h;
        ql[dt][j] = (short)f2bf(x - bf2f(h));
      }
    }
  }

  f32x16 o0, o1;
#pragma unroll
  for (int r = 0; r < 16; ++r) { o0[r] = 0.f; o1[r] = 0.f; }
  float m = -1e30f, lsum = 0.f;

  const int nch = (vlen + CH - 1) / CH;
  const short* tbase = wsT + (size_t)b * NKT * TILE_SHORTS;

  uv4 rg[8];
  auto issue = [&](int ci) {
    const uv4* g = (const uv4*)(tbase + (size_t)ci * TILE_SHORTS);
#pragma unroll
    for (int j = 0; j < 8; ++j) rg[j] = g[tid + j * 128];
  };
  issue(0);

  for (int ci = 0; ci < nch; ++ci) {
    __syncthreads();  // everyone done reading previous chunk's sKV
    {
      uv4* d = (uv4*)sKV;
#pragma unroll
      for (int j = 0; j < 8; ++j) d[tid + j * 128] = rg[j];
    }
    __syncthreads();  // sKV visible block-wide
    if (ci + 1 < nch) issue(ci + 1);  // prefetch drains under compute

    // ---- QK^T: acc[key][qrow], A=K B=Q ----
    f32x16 acc;
#pragma unroll
    for (int r = 0; r < 16; ++r) acc[r] = 0.f;
    const bfrag* Kh = (const bfrag*)(sKV);
    const bfrag* Kl = (const bfrag*)(sKV + 2048);
#pragma unroll
    for (int dt = 0; dt < 4; ++dt) {
      bfrag kh = Kh[(dt * 2 + hi5) * 32 + l31];
      bfrag kl = Kl[(dt * 2 + hi5) * 32 + l31];
      acc = __builtin_amdgcn_mfma_f32_32x32x16_bf16(kh, qh[dt], acc, 0, 0, 0);
      acc = __builtin_amdgcn_mfma_f32_32x32x16_bf16(kh, ql[dt], acc, 0, 0, 0);
      acc = __builtin_amdgcn_mfma_f32_32x32x16_bf16(kl, qh[dt], acc, 0, 0, 0);
    }

    // ---- mask tail keys on the last partial chunk ----
    const int c0 = ci * CH;
    if (c0 + CH > vlen) {
#pragma unroll
      for (int r = 0; r < 16; ++r) {
        int key = c0 + (r & 3) + 8 * (r >> 2) + 4 * hi5;
        if (key >= vlen) acc[r] = -1e30f;
      }
    }

    // ---- online softmax (lane owns q-row l31; keys split across hi5) ----
    float cmax = acc[0];
#pragma unroll
    for (int r = 1; r < 16; ++r) cmax = fmaxf(cmax, acc[r]);
    cmax = fmaxf(cmax, __shfl_xor(cmax, 32));

    if (__any((int)(cmax > m + 8.0f))) {   // defer-max rescale (T13)
      float mn = fmaxf(m, cmax);
      float sc = __expf(m - mn);
      m = mn;
      lsum *= sc;
#pragma unroll
      for (int r = 0; r < 16; ++r) {       // redistribute to PV row layout
        float s2 = __shfl(sc, (r & 3) + 8 * (r >> 2) + 4 * hi5);
        o0[r] *= s2;
        o1[r] *= s2;
      }
    }

    float p[16];
    float ps = 0.f;
#pragma unroll
    for (int r = 0; r < 16; ++r) {
      p[r] = __expf(acc[r] - m);
      ps += p[r];
    }
    ps += __shfl_xor(ps, 32);
    lsum += ps;

    // ---- P -> bf16 hi/lo -> per-wave LDS (A-fragment layout) ----
#pragma unroll
    for (int k8 = 0; k8 < 4; ++k8) {
      sv4 hv, lv;
#pragma unroll
      for (int j = 0; j < 4; ++j) {
        float pv = p[k8 * 4 + j];
        unsigned short h = f2bf(pv);
        hv[j] = (short)h;
        lv[j] = (short)f2bf(pv - bf2f(h));
      }
      *(sv4*)&sP[w][0][k8][l31][hi5 * 4] = hv;
      *(sv4*)&sP[w][1][k8][l31][hi5 * 4] = lv;
    }

    // ---- PV: o += P * V  (A=P, B=V) ----
    const bfrag* Vh = (const bfrag*)(sKV + 4096);
    const bfrag* Vl = (const bfrag*)(sKV + 6144);
#pragma unroll
    for (int ks = 0; ks < 2; ++ks) {
      bfrag ph = *(const bfrag*)&sP[w][0][ks * 2 + hi5][l31][0];
      bfrag pl = *(const bfrag*)&sP[w][1][ks * 2 + hi5][l31][0];
      bfrag vh0 = Vh[(ks * 2 + hi5) * 64 + l31];
      bfrag vl0 = Vl[(ks * 2 + hi5) * 64 + l31];
      bfrag vh1 = Vh[(ks * 2 + hi5) * 64 + 32 + l31];
      bfrag vl1 = Vl[(ks * 2 + hi5) * 64 + 32 + l31];
      o0 = __builtin_amdgcn_mfma_f32_32x32x16_bf16(ph, vh0, o0, 0, 0, 0);
      o0 = __builtin_amdgcn_mfma_f32_32x32x16_bf16(ph, vl0, o0, 0, 0, 0);
      o0 = __builtin_amdgcn_mfma_f32_32x32x16_bf16(pl, vh0, o0, 0, 0, 0);
      o1 = __builtin_amdgcn_mfma_f32_32x32x16_bf16(ph, vh1, o1, 0, 0, 0);
      o1 = __builtin_amdgcn_mfma_f32_32x32x16_bf16(ph, vl1, o1, 0, 0, 0);
      o1 = __builtin_amdgcn_mfma_f32_32x32x16_bf16(pl, vh1, o1, 0, 0, 0);
    }
  }

  // ---- epilogue: normalize and store ----
  const float linv = 1.0f / lsum;
  float* ob = Out + ((size_t)b * SS + qt * 64 + w * 32) * DH;
#pragma unroll
  for (int r = 0; r < 16; ++r) {
    int row = (r & 3) + 8 * (r >> 2) + 4 * hi5;
    float li = __shfl(linv, row);
    ob[row * DH + l31]      = o0[r] * li;
    ob[row * DH + 32 + l31] = o1[r] * li;
  }
}

// ---------------- emergency fallback (ws too small): naive flash ----------------
__global__ __launch_bounds__(256) void attn_naive(
    const float* __restrict__ Q, const float* __restrict__ K,
    const float* __restrict__ V, const int* __restrict__ VL,
    float* __restrict__ Out) {
  const int row = blockIdx.x * 256 + threadIdx.x;
  const int b = row >> 12;
  const int vlen = VL[b];
  const float* q = Q + (size_t)row * DH;
  float qr[DH];
#pragma unroll
  for (int d = 0; d < DH; ++d) qr[d] = q[d] * 0.125f;
  float m = -1e30f, ls = 0.f, o[DH];
#pragma unroll
  for (int d = 0; d < DH; ++d) o[d] = 0.f;
  const float* Kb = K + (size_t)b * SS * DH;
  const float* Vb = V + (size_t)b * SS * DH;
  for (int k = 0; k < vlen; ++k) {
    float s = 0.f;
    for (int d = 0; d < DH; ++d) s += qr[d] * Kb[(size_t)k * DH + d];
    if (s > m) {
      float sc = __expf(m - s);
      m = s;
      ls *= sc;
      for (int d = 0; d < DH; ++d) o[d] *= sc;
    }
    float p = __expf(s - m);
    ls += p;
    for (int d = 0; d < DH; ++d) o[d] += p * Vb[(size_t)k * DH + d];
  }
  for (int d = 0; d < DH; ++d) Out[(size_t)row * DH + d] = o[d] / ls;
}

extern "C" void kernel_launch(void* const* d_in, const int* in_sizes, int n_in,
                              void* d_out, int out_size, void* d_ws,
                              size_t ws_size, hipStream_t stream) {
  const float* Q  = (const float*)d_in[0];
  const float* K  = (const float*)d_in[1];
  const float* V  = (const float*)d_in[2];
  const int*   VL = (const int*)d_in[3];
  float* Out = (float*)d_out;

  const size_t need = (size_t)BB * NKT * TILE_SHORTS * sizeof(short);  // 16 MB
  if (ws_size >= need) {
    prepack<<<dim3(BB * NKT), dim3(256), 0, stream>>>(K, V, (short*)d_ws);
    attn_mfma<<<dim3(BB * (SS / 64)), dim3(128), 0, stream>>>(
        Q, (const short*)d_ws, VL, Out);
  } else {
    attn_naive<<<dim3(BB * SS / 256), dim3(256), 0, stream>>>(Q, K, V, VL, Out);
  }
}

// Round 3
// 179.568 us; speedup vs baseline: 1.2147x; 1.2147x over previous
//
#include <hip/hip_runtime.h>
#include <stdint.h>

// DotProductAttention, B=8 S=4096 D=64 fp32, key-masked at valid_len[b].
// Error-compensated bf16 MFMA flash attention, v2:
//  - prepack: K,V -> bf16 hi/lo tiles in ws (16KB per 32-key chunk), layout
//    matches MFMA fragment reads exactly (linear for global_load_lds).
//  - attn: 512 blocks x 256 thr = 4 waves: 2 row-groups x 2 key-stripe pairs.
//    Pair-local double-buffered LDS chunks staged via global_load_lds(16B).
//    Swapped QK^T (mfma(K,Q)) -> P is lane-local; PV A-fragments built
//    IN-REGISTER via v_cvt_pk_bf16_f32 + v_permlane32_swap_b32 (no P LDS
//    round-trip). Online softmax with defer-max (THR=8). Pair combine in LDS.

constexpr int BB = 8;
constexpr int SS = 4096;
constexpr int DH = 64;
constexpr int CH = 32;              // keys per chunk
constexpr int NKT = SS / CH;        // 128 chunks per batch
constexpr int TILE_SHORTS = 8192;   // 16 KB: Khi 4K | Klo 4K | Vhi 4K | Vlo 4K

typedef short  bfrag  __attribute__((ext_vector_type(8)));   // 8 bf16
typedef float  f32x16 __attribute__((ext_vector_type(16)));
typedef unsigned int uvec4 __attribute__((ext_vector_type(4)));

__device__ __forceinline__ unsigned short f2bf(float x) {
  unsigned u = __builtin_bit_cast(unsigned, x);
  u += 0x7fffu + ((u >> 16) & 1u);   // RNE
  return (unsigned short)(u >> 16);
}
__device__ __forceinline__ float bf2f(unsigned short h) {
  return __builtin_bit_cast(float, ((unsigned)h) << 16);
}

// ---------------- pre-pass: split+tile K and V (unchanged, verified) --------
__global__ __launch_bounds__(256) void prepack(
    const float* __restrict__ K, const float* __restrict__ V,
    short* __restrict__ ws) {
  const int b  = blockIdx.x >> 7;
  const int kt = blockIdx.x & 127;
  const int t  = threadIdx.x;
  short* tile = ws + (size_t)(b * NKT + kt) * TILE_SHORTS;

  {  // K unit t: d8 = t>>5, key = t&31
    const int d8 = t >> 5, key = t & 31;
    const float* src = K + ((size_t)b * SS + kt * CH + key) * DH + d8 * 8;
    float4 a = ((const float4*)src)[0];
    float4 c = ((const float4*)src)[1];
    float v[8] = {a.x, a.y, a.z, a.w, c.x, c.y, c.z, c.w};
    bfrag hi, lo;
#pragma unroll
    for (int j = 0; j < 8; ++j) {
      unsigned short h = f2bf(v[j]);
      hi[j] = (short)h;
      lo[j] = (short)f2bf(v[j] - bf2f(h));
    }
    *(bfrag*)(tile + t * 8)        = hi;
    *(bfrag*)(tile + 2048 + t * 8) = lo;
  }
  {  // V unit t: k8 = t>>6, d = t&63
    const int k8 = t >> 6, d = t & 63;
    const float* src = V + ((size_t)b * SS + kt * CH + k8 * 8) * DH + d;
    bfrag hi, lo;
#pragma unroll
    for (int j = 0; j < 8; ++j) {
      float x = src[j * DH];
      unsigned short h = f2bf(x);
      hi[j] = (short)h;
      lo[j] = (short)f2bf(x - bf2f(h));
    }
    *(bfrag*)(tile + 4096 + t * 8) = hi;
    *(bfrag*)(tile + 6144 + t * 8) = lo;
  }
}

// ---------------- main fused attention ----------------
__global__ __launch_bounds__(256) void attn_mfma(
    const float* __restrict__ Q, const short* __restrict__ wsT,
    const int* __restrict__ VL, float* __restrict__ Out) {
  // [pair][dbuf][tile] = 64 KB exactly; epilogue overlays the same memory.
  __shared__ __align__(16) short sKV[2][2][TILE_SHORTS];

  const int tid = threadIdx.x;
  const int w   = tid >> 6;
  const int l   = tid & 63;
  const int rg  = w & 1;    // row group: rows rg*32..+31
  const int p   = w >> 1;   // key-stripe pair: chunks == p (mod 2)
  const int hi5 = l >> 5;
  const int l31 = l & 31;
  const int b   = blockIdx.x & 7;   // batch interleaved for load balance
  const int qt  = blockIdx.x >> 3;
  const int vlen = VL[b];
  const int nch  = (vlen + CH - 1) / CH;

  // ---- Q fragments (B-operand: col=l31=q-row), pre-scaled by 1/8 ----
  bfrag qh[4], ql[4];
  {
    const float* qsrc = Q + ((size_t)b * SS + qt * 64 + rg * 32 + l31) * DH;
#pragma unroll
    for (int dt = 0; dt < 4; ++dt) {
      const float* pp = qsrc + dt * 16 + hi5 * 8;
      float4 a = ((const float4*)pp)[0];
      float4 c = ((const float4*)pp)[1];
      float v[8] = {a.x, a.y, a.z, a.w, c.x, c.y, c.z, c.w};
#pragma unroll
      for (int j = 0; j < 8; ++j) {
        float x = v[j] * 0.125f;
        unsigned short h = f2bf(x);
        qh[dt][j] = (short)h;
        ql[dt][j] = (short)f2bf(x - bf2f(h));
      }
    }
  }

  f32x16 o0, o1;
#pragma unroll
  for (int r = 0; r < 16; ++r) { o0[r] = 0.f; o1[r] = 0.f; }
  float m = -1e30f, lsum = 0.f;

  const short* tbase = wsT + (size_t)b * NKT * TILE_SHORTS;

  // stage chunk ci into sKV[p][buf]: pair's 2 waves split 16 slots of 1KB
  auto stage = [&](int ci, int buf) {
    const short* g = tbase + (size_t)ci * TILE_SHORTS + l * 8;
    short* dst = &sKV[p][buf][0];
#pragma unroll
    for (int j = 0; j < 8; ++j) {
      const int s = j * 2 + rg;
      __builtin_amdgcn_global_load_lds(
          (const __attribute__((address_space(1))) void*)(g + s * 512),
          (__attribute__((address_space(3))) void*)(dst + s * 512),
          16, 0, 0);
    }
  };

  if (p < nch) stage(p, 0);

  const int T = (nch + 1) >> 1;
  for (int t = 0; t < T; ++t) {
    __syncthreads();  // implicit vmcnt(0)+lgkmcnt(0): staged data ready,
                      // previous buffer's reads fully drained
    const int ci  = 2 * t + p;
    const int cur = t & 1;
    if (ci + 2 < nch) stage(ci + 2, cur ^ 1);  // prefetch flies under compute
    if (ci < nch) {
      const short* t0 = &sKV[p][cur][0];

      // ---- QK^T: acc[key][qrow], A=K B=Q; two 6-chains ----
      f32x16 accA, accB;
#pragma unroll
      for (int r = 0; r < 16; ++r) { accA[r] = 0.f; accB[r] = 0.f; }
#pragma unroll
      for (int dt = 0; dt < 4; ++dt) {
        bfrag kh = *(const bfrag*)(t0 + ((2 * dt + hi5) * 32 + l31) * 8);
        bfrag kl = *(const bfrag*)(t0 + 2048 + ((2 * dt + hi5) * 32 + l31) * 8);
        accA = __builtin_amdgcn_mfma_f32_32x32x16_bf16(kh, qh[dt], accA, 0, 0, 0);
        if (dt < 2)
          accA = __builtin_amdgcn_mfma_f32_32x32x16_bf16(kh, ql[dt], accA, 0, 0, 0);
        else
          accB = __builtin_amdgcn_mfma_f32_32x32x16_bf16(kh, ql[dt], accB, 0, 0, 0);
        accB = __builtin_amdgcn_mfma_f32_32x32x16_bf16(kl, qh[dt], accB, 0, 0, 0);
      }
      float s[16];
#pragma unroll
      for (int r = 0; r < 16; ++r) s[r] = accA[r] + accB[r];

      // ---- mask tail keys ----
      const int c0 = ci * CH;
      if (c0 + CH > vlen) {
#pragma unroll
        for (int r = 0; r < 16; ++r) {
          int key = c0 + (r & 3) + 8 * (r >> 2) + 4 * hi5;
          if (key >= vlen) s[r] = -1e30f;
        }
      }

      // ---- online softmax (lane owns q-row l31) ----
      float cmax = s[0];
#pragma unroll
      for (int r = 1; r < 16; ++r) cmax = fmaxf(cmax, s[r]);
      cmax = fmaxf(cmax, __shfl_xor(cmax, 32));

      if (__any((int)(cmax > m + 8.0f))) {  // defer-max (T13)
        float mn = fmaxf(m, cmax);
        float sc = __expf(m - mn);
        m = mn;
        lsum *= sc;
#pragma unroll
        for (int r = 0; r < 16; ++r) {
          float s2 = __shfl(sc, (r & 3) + 8 * (r >> 2) + 4 * hi5);
          o0[r] *= s2;
          o1[r] *= s2;
        }
      }

      float ps = 0.f;
#pragma unroll
      for (int r = 0; r < 16; ++r) {
        s[r] = __expf(s[r] - m);
        ps += s[r];
      }
      ps += __shfl_xor(ps, 32);
      lsum += ps;

      // ---- P -> in-register A-fragments (T12: cvt_pk + permlane32_swap) ----
      unsigned wh[8], wl[8];
#pragma unroll
      for (int i = 0; i < 8; ++i) {
        float p0 = s[2 * i], p1 = s[2 * i + 1];
        unsigned hw;
        asm("v_cvt_pk_bf16_f32 %0, %1, %2" : "=v"(hw) : "v"(p0), "v"(p1));
        float h0 = __builtin_bit_cast(float, hw << 16);
        float h1 = __builtin_bit_cast(float, hw & 0xffff0000u);
        float r0 = p0 - h0, r1 = p1 - h1;
        unsigned lw;
        asm("v_cvt_pk_bf16_f32 %0, %1, %2" : "=v"(lw) : "v"(r0), "v"(r1));
        wh[i] = hw;
        wl[i] = lw;
      }
      // swap X<->Y halves: frag(ks) = [X', Y'] (derivation in notes; X=p[8k..+3])
      asm("v_permlane32_swap_b32 %0, %1" : "+v"(wh[0]), "+v"(wh[2]));
      asm("v_permlane32_swap_b32 %0, %1" : "+v"(wh[1]), "+v"(wh[3]));
      asm("v_permlane32_swap_b32 %0, %1" : "+v"(wh[4]), "+v"(wh[6]));
      asm("v_permlane32_swap_b32 %0, %1" : "+v"(wh[5]), "+v"(wh[7]));
      asm("v_permlane32_swap_b32 %0, %1" : "+v"(wl[0]), "+v"(wl[2]));
      asm("v_permlane32_swap_b32 %0, %1" : "+v"(wl[1]), "+v"(wl[3]));
      asm("v_permlane32_swap_b32 %0, %1" : "+v"(wl[4]), "+v"(wl[6]));
      asm("v_permlane32_swap_b32 %0, %1" : "+v"(wl[5]), "+v"(wl[7]));
      bfrag ph[2], pl[2];
      {
        uvec4 u0 = {wh[0], wh[1], wh[2], wh[3]};
        uvec4 u1 = {wh[4], wh[5], wh[6], wh[7]};
        uvec4 u2 = {wl[0], wl[1], wl[2], wl[3]};
        uvec4 u3 = {wl[4], wl[5], wl[6], wl[7]};
        ph[0] = __builtin_bit_cast(bfrag, u0);
        ph[1] = __builtin_bit_cast(bfrag, u1);
        pl[0] = __builtin_bit_cast(bfrag, u2);
        pl[1] = __builtin_bit_cast(bfrag, u3);
      }

      // ---- PV: o += P * V (A=P, B=V); two independent 6-chains ----
#pragma unroll
      for (int ks = 0; ks < 2; ++ks) {
        const int vo = ((2 * ks + hi5) * 64 + l31) * 8;
        bfrag vh0 = *(const bfrag*)(t0 + 4096 + vo);
        bfrag vl0 = *(const bfrag*)(t0 + 6144 + vo);
        bfrag vh1 = *(const bfrag*)(t0 + 4096 + vo + 256);
        bfrag vl1 = *(const bfrag*)(t0 + 6144 + vo + 256);
        o0 = __builtin_amdgcn_mfma_f32_32x32x16_bf16(ph[ks], vh0, o0, 0, 0, 0);
        o0 = __builtin_amdgcn_mfma_f32_32x32x16_bf16(ph[ks], vl0, o0, 0, 0, 0);
        o0 = __builtin_amdgcn_mfma_f32_32x32x16_bf16(pl[ks], vh0, o0, 0, 0, 0);
        o1 = __builtin_amdgcn_mfma_f32_32x32x16_bf16(ph[ks], vh1, o1, 0, 0, 0);
        o1 = __builtin_amdgcn_mfma_f32_32x32x16_bf16(ph[ks], vl1, o1, 0, 0, 0);
        o1 = __builtin_amdgcn_mfma_f32_32x32x16_bf16(pl[ks], vh1, o1, 0, 0, 0);
      }
    }
  }

  // ---- epilogue: pair combine in (overlaid) LDS, normalize, store ----
  float* fl = (float*)&sKV[0][0][0];
  // layout: m[2][64] at 0, l[2][64] at 128, C[2][32][64] at 256
  __syncthreads();  // all sKV chunk use done
  if (hi5 == 0) {
    fl[p * 64 + rg * 32 + l31]       = m;
    fl[128 + p * 64 + rg * 32 + l31] = lsum;
  }
  __syncthreads();
  const float mo = fl[(p ^ 1) * 64 + rg * 32 + l31];
  const float lo = fl[128 + (p ^ 1) * 64 + rg * 32 + l31];
  const float M  = fmaxf(m, mo);
  const float wgt = __expf(m - M);
  const float Lsum = lsum * wgt + lo * __expf(mo - M);
  const float linv = 1.0f / Lsum;
  float* C = fl + 256 + rg * 2048;
  if (p == 1) {
#pragma unroll
    for (int r = 0; r < 16; ++r) {
      int row = (r & 3) + 8 * (r >> 2) + 4 * hi5;
      float wr = __shfl(wgt, row);
      C[row * 64 + l31]      = wr * o0[r];
      C[row * 64 + 32 + l31] = wr * o1[r];
    }
  }
  __syncthreads();
  if (p == 0) {
    float* ob = Out + ((size_t)b * SS + qt * 64 + rg * 32) * DH;
#pragma unroll
    for (int r = 0; r < 16; ++r) {
      int row = (r & 3) + 8 * (r >> 2) + 4 * hi5;
      float wr = __shfl(wgt, row);
      float li = __shfl(linv, row);
      ob[row * DH + l31]      = (wr * o0[r] + C[row * 64 + l31]) * li;
      ob[row * DH + 32 + l31] = (wr * o1[r] + C[row * 64 + 32 + l31]) * li;
    }
  }
}

// ---------------- emergency fallback (ws too small): naive flash ------------
__global__ __launch_bounds__(256) void attn_naive(
    const float* __restrict__ Q, const float* __restrict__ K,
    const float* __restrict__ V, const int* __restrict__ VL,
    float* __restrict__ Out) {
  const int row = blockIdx.x * 256 + threadIdx.x;
  const int b = row >> 12;
  const int vlen = VL[b];
  const float* q = Q + (size_t)row * DH;
  float qr[DH];
#pragma unroll
  for (int d = 0; d < DH; ++d) qr[d] = q[d] * 0.125f;
  float m = -1e30f, ls = 0.f, o[DH];
#pragma unroll
  for (int d = 0; d < DH; ++d) o[d] = 0.f;
  const float* Kb = K + (size_t)b * SS * DH;
  const float* Vb = V + (size_t)b * SS * DH;
  for (int k = 0; k < vlen; ++k) {
    float sc = 0.f;
    for (int d = 0; d < DH; ++d) sc += qr[d] * Kb[(size_t)k * DH + d];
    if (sc > m) {
      float scale = __expf(m - sc);
      m = sc;
      ls *= scale;
      for (int d = 0; d < DH; ++d) o[d] *= scale;
    }
    float pv = __expf(sc - m);
    ls += pv;
    for (int d = 0; d < DH; ++d) o[d] += pv * Vb[(size_t)k * DH + d];
  }
  for (int d = 0; d < DH; ++d) Out[(size_t)row * DH + d] = o[d] / ls;
}

extern "C" void kernel_launch(void* const* d_in, const int* in_sizes, int n_in,
                              void* d_out, int out_size, void* d_ws,
                              size_t ws_size, hipStream_t stream) {
  const float* Q  = (const float*)d_in[0];
  const float* K  = (const float*)d_in[1];
  const float* V  = (const float*)d_in[2];
  const int*   VL = (const int*)d_in[3];
  float* Out = (float*)d_out;

  const size_t need = (size_t)BB * NKT * TILE_SHORTS * sizeof(short);  // 16 MB
  if (ws_size >= need) {
    prepack<<<dim3(BB * NKT), dim3(256), 0, stream>>>(K, V, (short*)d_ws);
    attn_mfma<<<dim3(BB * (SS / 64)), dim3(256), 0, stream>>>(
        Q, (const short*)d_ws, VL, Out);
  } else {
    attn_naive<<<dim3(BB * SS / 256), dim3(256), 0, stream>>>(Q, K, V, VL, Out);
  }
}